// Round 4
// baseline (805.117 us; speedup 1.0000x reference)
//
#include <hip/hip_runtime.h>
#include <math.h>

#define Bdim 16
#define Mdim 4096
#define Tdim 4
#define Ddim 256
#define Vdim 40000
#define CONVMAX 512
#define MT 64

typedef float f32x4 __attribute__((ext_vector_type(4)));
static __device__ inline void nt_store4(float* p, float4 v) {
    f32x4 x = {v.x, v.y, v.z, v.w};
    __builtin_nontemporal_store(x, (f32x4*)p);
}

// ---------------------------------------------------------------------------
// init: out_uf = query_vector    grid: B blocks, 256 threads
// ---------------------------------------------------------------------------
__global__ void init_kernel(const float* __restrict__ qv, float* __restrict__ uf) {
    int b = blockIdx.x, i = threadIdx.x;
    uf[(size_t)b * Ddim + i] = qv[(size_t)b * Ddim + i];
}

// ---------------------------------------------------------------------------
// dot: D[v*16+b] = tab[v,:] . uf[b,:]   (streaming 41 MB table pass)
//      Hdot[b*512+j] = hist[b,j,:] . uf[b,:]   (extra 16 blocks)
// grid: DV_BLOCKS + B blocks, 256 threads (wave per v-row, shfl reduce)
// ---------------------------------------------------------------------------
#define DV_VROWS 64
#define DV_BLOCKS (Vdim / DV_VROWS)   // 625
__global__ void dot_kernel(const float* __restrict__ tab, const float* __restrict__ uf,
                           const float* __restrict__ hist,
                           float* __restrict__ D, float* __restrict__ Hdot) {
    __shared__ __align__(16) float ufs[Bdim * Ddim];
    int tid = threadIdx.x;
#pragma unroll
    for (int k = 0; k < Bdim; ++k) ufs[k * Ddim + tid] = uf[k * Ddim + tid];
    __syncthreads();
    int wave = tid >> 6, lane = tid & 63;
    int bid = blockIdx.x;
    if (bid < DV_BLOCKS) {
        int v0 = bid * DV_VROWS + wave * (DV_VROWS / 4);
        for (int i = 0; i < DV_VROWS / 4; ++i) {
            int v = v0 + i;
            const float4 r = *(const float4*)(tab + (size_t)v * Ddim + lane * 4);
#pragma unroll
            for (int b = 0; b < Bdim; ++b) {
                const float4 u4 = *(const float4*)(&ufs[b * Ddim + lane * 4]);
                float s = r.x * u4.x + r.y * u4.y + r.z * u4.z + r.w * u4.w;
#pragma unroll
                for (int off = 32; off > 0; off >>= 1) s += __shfl_xor(s, off, 64);
                if (lane == 0) D[v * Bdim + b] = s;
            }
        }
    } else {
        int b = bid - DV_BLOCKS;
        for (int j = wave; j < CONVMAX; j += 4) {
            const float4 r = *(const float4*)(hist + ((size_t)b * CONVMAX + j) * Ddim + lane * 4);
            const float4 u4 = *(const float4*)(&ufs[b * Ddim + lane * 4]);
            float s = r.x * u4.x + r.y * u4.y + r.z * u4.z + r.w * u4.w;
#pragma unroll
            for (int off = 32; off > 0; off >>= 1) s += __shfl_xor(s, off, 64);
            if (lane == 0) Hdot[b * CONVMAX + j] = s;
        }
    }
}

// ---------------------------------------------------------------------------
// logit: logits[b,m] = gp * (sum_t D[st[t],b] + in_window * Hdot[b,m-kb])
// grid: B*M/256 blocks, 256 threads (thread per row)
// ---------------------------------------------------------------------------
__global__ void logit_kernel(const int* __restrict__ story, const int* __restrict__ kb_len,
                             const int* __restrict__ conv_len, const float* __restrict__ D,
                             const float* __restrict__ Hdot, const float* __restrict__ gp,
                             float* __restrict__ logits) {
    int row = blockIdx.x * 256 + threadIdx.x;
    int b = row >> 12, m = row & (Mdim - 1);
    const int4 st = *(const int4*)(story + (size_t)row * Tdim);
    float l = D[st.x * Bdim + b] + D[st.y * Bdim + b] + D[st.z * Bdim + b] + D[st.w * Bdim + b];
    unsigned j = (unsigned)(m - kb_len[b]);
    if (j < (unsigned)conv_len[b]) l += Hdot[b * CONVMAX + j];
    logits[row] = l * gp[row];
}

// ---------------------------------------------------------------------------
// stats (blocks < B) + zero w (blocks >= B).  grid: B + ZW_BLOCKS, 256 thr
// ---------------------------------------------------------------------------
#define ZW_BLOCKS (Vdim * Bdim / 1024)   // 625
__global__ void stats_zero_kernel(const float* __restrict__ logits, float* __restrict__ maxv,
                                  float* __restrict__ rsum, float* __restrict__ w) {
    int bid = blockIdx.x, tid = threadIdx.x;
    if (bid >= Bdim) {
        int idx = (bid - Bdim) * 1024 + tid * 4;
        *(float4*)(w + idx) = make_float4(0.f, 0.f, 0.f, 0.f);
        return;
    }
    __shared__ float sh[256];
    const float* lg = logits + (size_t)bid * Mdim;
    float mx = -INFINITY;
    for (int i = tid; i < Mdim; i += 256) mx = fmaxf(mx, lg[i]);
    sh[tid] = mx; __syncthreads();
    for (int s = 128; s > 0; s >>= 1) { if (tid < s) sh[tid] = fmaxf(sh[tid], sh[tid + s]); __syncthreads(); }
    float bm = sh[0]; __syncthreads();
    float sm = 0.f;
    for (int i = tid; i < Mdim; i += 256) sm += expf(lg[i] - bm);
    sh[tid] = sm; __syncthreads();
    for (int s = 128; s > 0; s >>= 1) { if (tid < s) sh[tid] += sh[tid + s]; __syncthreads(); }
    if (tid == 0) { maxv[bid] = bm; rsum[bid] = 1.0f / sh[0]; }
}

// ---------------------------------------------------------------------------
// scatter: p = softmax(l)*gp; w[st[t],b] += p (x4 atomics); pwin for window
// grid: B*M/256 blocks, 256 threads (thread per row)
// ---------------------------------------------------------------------------
__global__ void scatter_kernel(const int* __restrict__ story, const int* __restrict__ kb_len,
                               const int* __restrict__ conv_len, const float* __restrict__ logits,
                               const float* __restrict__ maxv, const float* __restrict__ rsum,
                               const float* __restrict__ gp, float* __restrict__ w,
                               float* __restrict__ pwin) {
    int row = blockIdx.x * 256 + threadIdx.x;
    int b = row >> 12, m = row & (Mdim - 1);
    float p = expf(logits[row] - maxv[b]) * rsum[b] * gp[row];
    const int4 st = *(const int4*)(story + (size_t)row * Tdim);
    atomicAdd(&w[st.x * Bdim + b], p);
    atomicAdd(&w[st.y * Bdim + b], p);
    atomicAdd(&w[st.z * Bdim + b], p);
    atomicAdd(&w[st.w * Bdim + b], p);
    unsigned j = (unsigned)(m - kb_len[b]);
    if (j < (unsigned)conv_len[b]) pwin[b * CONVMAX + j] = p;
}

// ---------------------------------------------------------------------------
// wsum: uf[b,:] += sum_v w[v,b]*tab[v,:]  (streaming 41 MB table pass)
//       + hist window contribution (extra 16 blocks)
// grid: WS_BLOCKS + B blocks, 256 threads (thread per d, shfl-broadcast w)
// ---------------------------------------------------------------------------
#define WS_VROWS 64
#define WS_BLOCKS (Vdim / WS_VROWS)   // 625
__global__ void wsum_kernel(const float* __restrict__ tab, const float* __restrict__ w,
                            const float* __restrict__ pwin, const float* __restrict__ hist,
                            const int* __restrict__ conv_len, float* __restrict__ uf) {
    int tid = threadIdx.x, lane = tid & 63;
    int bid = blockIdx.x;
    if (bid < WS_BLOCKS) {
        float acc[Bdim];
#pragma unroll
        for (int b = 0; b < Bdim; ++b) acc[b] = 0.f;
        int v0 = bid * WS_VROWS;
        for (int v = v0; v < v0 + WS_VROWS; ++v) {
            float wv = (lane < Bdim) ? w[v * Bdim + lane] : 0.f;
            float tv = tab[(size_t)v * Ddim + tid];
#pragma unroll
            for (int b = 0; b < Bdim; ++b) acc[b] += __shfl(wv, b, 64) * tv;
        }
#pragma unroll
        for (int b = 0; b < Bdim; ++b) atomicAdd(&uf[b * Ddim + tid], acc[b]);
    } else {
        int b = bid - WS_BLOCKS;
        int cl = conv_len[b];
        float acc = 0.f;
        for (int j = 0; j < cl; ++j)
            acc += pwin[b * CONVMAX + j] * hist[((size_t)b * CONVMAX + j) * Ddim + tid];
        atomicAdd(&uf[b * Ddim + tid], acc);
    }
}

// ---------------------------------------------------------------------------
// att: final hop only — recompute e3(row) by gather; prob = softmax*gp;
//      uf += sum_m prob*e3;  write e3 to out_m (NT) and psoft (NT).
// grid: B*(M/MT) blocks, 256 threads (wave per row, float4 per lane)
// ---------------------------------------------------------------------------
__global__ void att_kernel(const int* __restrict__ story, const int* __restrict__ kb_len,
                           const int* __restrict__ conv_len, const float* __restrict__ hist,
                           const float* __restrict__ tab, const float* __restrict__ logits,
                           const float* __restrict__ maxv, const float* __restrict__ rsum,
                           const float* __restrict__ gp,
                           float* __restrict__ uf_acc, float* __restrict__ out_m,
                           float* __restrict__ out_psoft) {
    int bid = blockIdx.x;
    int b  = bid / (Mdim / MT);
    int m0 = (bid % (Mdim / MT)) * MT;
    int tid = threadIdx.x, wave = tid >> 6, lane = tid & 63;
    int d4 = lane * 4;
    __shared__ float prob[MT];
    __shared__ float4 red[4][64];
    if (tid < MT) {
        size_t row = (size_t)b * Mdim + m0 + tid;
        float pn = expf(logits[row] - maxv[b]) * rsum[b];
        __builtin_nontemporal_store(pn, out_psoft + row);
        prob[tid] = pn * gp[row];
    }
    __syncthreads();
    int kb = kb_len[b], cl = conv_len[b];
    float4 acc = make_float4(0.f, 0.f, 0.f, 0.f);
#pragma unroll 4
    for (int mm = wave; mm < MT; mm += 4) {
        int m = m0 + mm;
        size_t row = (size_t)b * Mdim + m;
        const int* st = story + row * Tdim;
        float4 v = make_float4(0.f, 0.f, 0.f, 0.f);
#pragma unroll
        for (int t = 0; t < Tdim; ++t) {
            const float4 wv = *(const float4*)(tab + (size_t)st[t] * Ddim + d4);
            v.x += wv.x; v.y += wv.y; v.z += wv.z; v.w += wv.w;
        }
        if (m >= kb && m < kb + cl) {
            const float4 h = *(const float4*)(hist + ((size_t)b * CONVMAX + (m - kb)) * Ddim + d4);
            v.x += h.x; v.y += h.y; v.z += h.z; v.w += h.w;
        }
        nt_store4(out_m + row * Ddim + d4, v);
        float p = prob[mm];
        acc.x += p * v.x; acc.y += p * v.y; acc.z += p * v.z; acc.w += p * v.w;
    }
    red[wave][lane] = acc;
    __syncthreads();
    if (wave == 0) {
        float4 a0 = red[0][lane], a1 = red[1][lane], a2 = red[2][lane], a3 = red[3][lane];
        float* dst = uf_acc + (size_t)b * Ddim + d4;
        atomicAdd(dst + 0, a0.x + a1.x + a2.x + a3.x);
        atomicAdd(dst + 1, a0.y + a1.y + a2.y + a3.y);
        atomicAdd(dst + 2, a0.z + a1.z + a2.z + a3.z);
        atomicAdd(dst + 3, a0.w + a1.w + a2.w + a3.w);
    }
}

extern "C" void kernel_launch(void* const* d_in, const int* in_sizes, int n_in,
                              void* d_out, int out_size, void* d_ws, size_t ws_size,
                              hipStream_t stream) {
    const int*   story        = (const int*)d_in[0];
    const int*   kb_len       = (const int*)d_in[1];
    const int*   conv_len     = (const int*)d_in[2];
    // d_in[3] (query), d_in[8..11] (Tg_w, Tg_b, FW_w, FW_b): dead w.r.t. outputs
    const float* hist         = (const float*)d_in[4];
    const float* query_vector = (const float*)d_in[5];
    const float* gp           = (const float*)d_in[6];
    const float* C_emb        = (const float*)d_in[7];

    float* out        = (float*)d_out;
    float* out_psoft  = out;                                   // B*M
    float* out_logits = out + (size_t)Bdim * Mdim;             // B*M
    float* out_uf     = out + 2 * (size_t)Bdim * Mdim;         // B*D
    float* out_m      = out + 2 * (size_t)Bdim * Mdim + (size_t)Bdim * Ddim; // B*M*D

    float* ws = (float*)d_ws;
    float* D      = ws;                              // V*B      (640000)
    float* w      = D + (size_t)Vdim * Bdim;         // V*B      (640000)
    float* Hdot   = w + (size_t)Vdim * Bdim;         // B*CONVMAX
    float* pwin   = Hdot + Bdim * CONVMAX;           // B*CONVMAX
    float* logits = pwin + Bdim * CONVMAX;           // B*M
    float* maxv   = logits + (size_t)Bdim * Mdim;    // B
    float* rsum   = maxv + Bdim;                     // B

    const size_t TAB = (size_t)Vdim * Ddim;
    const float* tab0 = C_emb;
    const float* tab1 = C_emb + TAB;
    const float* tab2 = C_emb + 2 * TAB;
    const float* tab3 = C_emb + 3 * TAB;

    const int ROW_GRID = Bdim * Mdim / 256;          // 256
    const int DOT_GRID = DV_BLOCKS + Bdim;           // 641
    const int SZ_GRID  = Bdim + ZW_BLOCKS;           // 641
    const int WS_GRID  = WS_BLOCKS + Bdim;           // 641
    const int ATT_GRID = Bdim * (Mdim / MT);         // 1024

    init_kernel<<<Bdim, Ddim, 0, stream>>>(query_vector, out_uf);

    // hops 0 and 1: table-level passes only (no row gathers)
    const float* qtab[3]  = { tab0, tab1, tab2 };
    const float* vtab[3]  = { tab1, tab2, tab3 };
    for (int h = 0; h < 2; ++h) {
        dot_kernel<<<DOT_GRID, 256, 0, stream>>>(qtab[h], out_uf, hist, D, Hdot);
        logit_kernel<<<ROW_GRID, 256, 0, stream>>>(story, kb_len, conv_len, D, Hdot, gp, logits);
        stats_zero_kernel<<<SZ_GRID, 256, 0, stream>>>(logits, maxv, rsum, w);
        scatter_kernel<<<ROW_GRID, 256, 0, stream>>>(story, kb_len, conv_len, logits,
                                                     maxv, rsum, gp, w, pwin);
        wsum_kernel<<<WS_GRID, 256, 0, stream>>>(vtab[h], w, pwin, hist, conv_len, out_uf);
    }

    // hop 2: logits/psoft are outputs; out_m forces one real gather pass
    dot_kernel<<<DOT_GRID, 256, 0, stream>>>(tab2, out_uf, hist, D, Hdot);
    logit_kernel<<<ROW_GRID, 256, 0, stream>>>(story, kb_len, conv_len, D, Hdot, gp, out_logits);
    stats_zero_kernel<<<SZ_GRID, 256, 0, stream>>>(out_logits, maxv, rsum, w);
    att_kernel<<<ATT_GRID, 256, 0, stream>>>(story, kb_len, conv_len, hist, tab3,
                                             out_logits, maxv, rsum, gp,
                                             out_uf, out_m, out_psoft);
}